// Round 5
// baseline (588.882 us; speedup 1.0000x reference)
//
#include <hip/hip_runtime.h>

#define D 32
#define NPB 64                      // nodes per fused block (dst-local fits 6 bits)
#define SRC_BITS 25
#define SRC_MASK ((1 << SRC_BITS) - 1)
#define SCAN_CHUNK 1024

__device__ __forceinline__ float relu_f(float v) { return v > 0.f ? v : 0.f; }

// round-to-nearest-even f32 -> bf16 bits
__device__ __forceinline__ unsigned bf16_rne(float f) {
    unsigned u = __float_as_uint(f);
    return (u + 0x7FFFu + ((u >> 16) & 1u)) >> 16;
}

// ============================ preprocessing =============================
__global__ void __launch_bounds__(256) hist_kernel(
    const int* __restrict__ dst, int* __restrict__ deg, int E)
{
    int e = blockIdx.x * 256 + threadIdx.x;
    if (e < E) atomicAdd(&deg[dst[e]], 1);
}

__global__ void __launch_bounds__(256) scan_partial_kernel(
    const int* __restrict__ deg, int* __restrict__ part, int N)
{
    __shared__ int s[256];
    int t = threadIdx.x;
    int base = blockIdx.x * SCAN_CHUNK + t * 4;
    int sum = 0;
    #pragma unroll
    for (int i = 0; i < 4; ++i) { int idx = base + i; if (idx < N) sum += deg[idx]; }
    s[t] = sum;
    __syncthreads();
    for (int off = 128; off > 0; off >>= 1) {
        if (t < off) s[t] += s[t + off];
        __syncthreads();
    }
    if (t == 0) part[blockIdx.x] = s[0];
}

__global__ void scan_part_exclusive_kernel(int* part, int nb)
{
    if (threadIdx.x == 0 && blockIdx.x == 0) {
        int run = 0;
        for (int i = 0; i < nb; ++i) { int v = part[i]; part[i] = run; run += v; }
    }
}

__global__ void __launch_bounds__(256) scan_final_kernel(
    int* __restrict__ rowdeg, const int* __restrict__ part, int N)
{
    __shared__ int s[256];
    int t = threadIdx.x;
    int base = blockIdx.x * SCAN_CHUNK + t * 4;
    int d0 = 0, d1 = 0, d2 = 0, d3 = 0;
    if (base + 0 < N) d0 = rowdeg[base + 0];
    if (base + 1 < N) d1 = rowdeg[base + 1];
    if (base + 2 < N) d2 = rowdeg[base + 2];
    if (base + 3 < N) d3 = rowdeg[base + 3];
    int tsum = d0 + d1 + d2 + d3;
    s[t] = tsum;
    __syncthreads();
    for (int off = 1; off < 256; off <<= 1) {
        int a = (t >= off) ? s[t - off] : 0;
        __syncthreads();
        s[t] += a;
        __syncthreads();
    }
    int excl = s[t] - tsum + part[blockIdx.x];
    if (base + 0 < N) rowdeg[base + 0] = excl;
    if (base + 1 < N) rowdeg[base + 1] = excl + d0;
    if (base + 2 < N) rowdeg[base + 2] = excl + d0 + d1;
    if (base + 3 < N) rowdeg[base + 3] = excl + d0 + d1 + d2;
}

// Slot claim only: turns row[] exclusive -> inclusive (fused kernel exploits
// that). Writes packed src + dst-local (4B) and the edge permutation (4B).
__global__ void __launch_bounds__(256) place_idx_kernel(
    const int* __restrict__ src, const int* __restrict__ dst,
    int* __restrict__ row, int* __restrict__ srcpk,
    int* __restrict__ eperm, int E)
{
    int e = blockIdx.x * 256 + threadIdx.x;
    if (e < E) {
        int d = dst[e];
        int pos = atomicAdd(&row[d], 1);
        srcpk[pos] = src[e] | ((d & (NPB - 1)) << SRC_BITS);
        eperm[pos] = e;
    }
}

// Sequential over sorted positions: gather fp32 ea row (one full 128B line,
// fully consumed -> no read amplification), convert to bf16, write eah
// COALESCED (full lines -> no write amplification).
__global__ void __launch_bounds__(256) gather_convert_kernel(
    const float* __restrict__ ea, const int* __restrict__ eperm,
    unsigned* __restrict__ eah, int E)
{
    int i = blockIdx.x * 256 + threadIdx.x;
    if (i >= E * 8) return;
    int p = i >> 3, q = i & 7;
    int e = eperm[p];                       // same addr across group: broadcast
    float4 v = reinterpret_cast<const float4*>(ea)[(size_t)e * 8 + q];
    uint2 w;
    w.x = bf16_rne(v.x) | (bf16_rne(v.y) << 16);
    w.y = bf16_rne(v.z) | (bf16_rne(v.w) << 16);
    reinterpret_cast<uint2*>(eah)[(size_t)p * 8 + q] = w;
}

// ========================= fused layer (v4) ============================
// Block = 256 thr = 32 groups of 8 lanes; block owns NPB=64 consecutive
// nodes + their contiguous dst-sorted edge range. Per 8-edge batch:
// PHASE 1 loads all 8 uint2 (bf16 ea) + 8 float4 (x rows, 128B/group)
// into statically-indexed registers -> 16 independent loads in flight;
// PHASE 2 does segmented register accumulation with rare LDS-atomic flush
// on dst change. MLP in-block after one barrier (W in LDS, lane j -> bank
// j conflict-free, broadcast reads free).
__global__ void __launch_bounds__(256) gine_fused4_kernel(
    const float* __restrict__ x, const unsigned* __restrict__ eah,
    const int* __restrict__ srcpk, const int* __restrict__ row,
    const float* __restrict__ W1, const float* __restrict__ b1,
    const float* __restrict__ W2, const float* __restrict__ b2,
    const float* __restrict__ eps, int l, float* __restrict__ out, int N)
{
    __shared__ float aggr[NPB][D];          // 8KB
    __shared__ float W1s[D * D], W2s[D * D];
    __shared__ float b1s[D], b2s[D];
    __shared__ float ys[8][D];

    int t = threadIdx.x;
    for (int i = t; i < D * D; i += 256) { W1s[i] = W1[i]; W2s[i] = W2[i]; }
    if (t < D) { b1s[t] = b1[t]; b2s[t] = b2[t]; }
    for (int i = t; i < NPB * D; i += 256) ((float*)aggr)[i] = 0.f;

    int g8 = t >> 3;                        // group 0..31
    int q  = t & 7;                         // lane in group; owns features 4q..4q+3
    int n0 = blockIdx.x * NPB;
    int nlast = min(n0 + NPB - 1, N - 1);
    int estart = n0 ? row[n0 - 1] : 0;      // row[] is inclusive prefix
    int eend   = row[nlast];
    __syncthreads();

    // -------- edge aggregation --------
    int EB = eend - estart;
    int chunk = (EB + 31) >> 5;
    int a = estart + g8 * chunk;
    int b = min(a + chunk, eend);

    float4 acc = make_float4(0.f, 0.f, 0.f, 0.f);
    int cur = -1;
    int k = a;
    while (k + 8 <= b) {
        int pv = srcpk[k + q];              // 8 packed indices, one 32B load
        uint2  w[8];
        float4 xv[8];
        int    pp[8];
        #pragma unroll
        for (int i = 0; i < 8; ++i) {       // PHASE 1: issue all loads
            int p  = __shfl(pv, i, 8);
            pp[i] = p;
            int s  = p & SRC_MASK;
            w[i]  = *reinterpret_cast<const uint2*>(eah + (size_t)(k + i) * 8 + q);
            xv[i] = *reinterpret_cast<const float4*>(x + (size_t)s * D + q * 4);
        }
        #pragma unroll
        for (int i = 0; i < 8; ++i) {       // PHASE 2: compute + rare flush
            int ld = (pp[i] >> SRC_BITS) & (NPB - 1);
            if (ld != cur) {
                if (cur >= 0) {
                    atomicAdd(&aggr[cur][q * 4 + 0], acc.x);
                    atomicAdd(&aggr[cur][q * 4 + 1], acc.y);
                    atomicAdd(&aggr[cur][q * 4 + 2], acc.z);
                    atomicAdd(&aggr[cur][q * 4 + 3], acc.w);
                }
                cur = ld;
                acc = make_float4(0.f, 0.f, 0.f, 0.f);
            }
            acc.x += relu_f(xv[i].x + __uint_as_float(w[i].x << 16));
            acc.y += relu_f(xv[i].y + __uint_as_float(w[i].x & 0xFFFF0000u));
            acc.z += relu_f(xv[i].z + __uint_as_float(w[i].y << 16));
            acc.w += relu_f(xv[i].w + __uint_as_float(w[i].y & 0xFFFF0000u));
        }
        k += 8;
    }
    while (k < b) {                          // tail (<8 edges)
        int p  = srcpk[k];                   // same addr across group: broadcast
        int s  = p & SRC_MASK;
        int ld = (p >> SRC_BITS) & (NPB - 1);
        uint2 w = *reinterpret_cast<const uint2*>(eah + (size_t)k * 8 + q);
        float4 xv = *reinterpret_cast<const float4*>(x + (size_t)s * D + q * 4);
        if (ld != cur) {
            if (cur >= 0) {
                atomicAdd(&aggr[cur][q * 4 + 0], acc.x);
                atomicAdd(&aggr[cur][q * 4 + 1], acc.y);
                atomicAdd(&aggr[cur][q * 4 + 2], acc.z);
                atomicAdd(&aggr[cur][q * 4 + 3], acc.w);
            }
            cur = ld;
            acc = make_float4(0.f, 0.f, 0.f, 0.f);
        }
        acc.x += relu_f(xv.x + __uint_as_float(w.x << 16));
        acc.y += relu_f(xv.y + __uint_as_float(w.x & 0xFFFF0000u));
        acc.z += relu_f(xv.z + __uint_as_float(w.y << 16));
        acc.w += relu_f(xv.w + __uint_as_float(w.y & 0xFFFF0000u));
        ++k;
    }
    if (cur >= 0) {
        atomicAdd(&aggr[cur][q * 4 + 0], acc.x);
        atomicAdd(&aggr[cur][q * 4 + 1], acc.y);
        atomicAdd(&aggr[cur][q * 4 + 2], acc.z);
        atomicAdd(&aggr[cur][q * 4 + 3], acc.w);
    }
    __syncthreads();

    // -------- MLP: half-wave hw owns nodes hw*8 .. hw*8+7 --------
    int hw = t >> 5, j = t & 31;
    float ep1 = 1.0f + eps[l];
    for (int r = 0; r < 8; ++r) {
        int ln = hw * 8 + r;
        int n = n0 + ln;
        if (n >= N) break;                  // no barriers below: safe
        float h = ep1 * x[(size_t)n * D + j] + aggr[ln][j];
        aggr[ln][j] = h;                    // stage for broadcast reads
        float a1 = b1s[j];
        #pragma unroll
        for (int kk = 0; kk < D; ++kk)
            a1 = fmaf(aggr[ln][kk], W1s[kk * D + j], a1);
        float y = relu_f(a1);
        ys[hw][j] = y;
        float a2 = b2s[j];
        #pragma unroll
        for (int kk = 0; kk < D; ++kk)
            a2 = fmaf(ys[hw][kk], W2s[kk * D + j], a2);
        out[(size_t)n * D + j] = relu_f(a2);
    }
}

// ================= fallback fused kernel (CSR gather path) =============
__global__ void __launch_bounds__(256) gine_fused_kernel(
    const float* __restrict__ x, const float* __restrict__ ea,
    const int* __restrict__ srcperm, const int* __restrict__ eperm,
    const int* __restrict__ row,
    const float* __restrict__ W1, const float* __restrict__ b1,
    const float* __restrict__ W2, const float* __restrict__ b2,
    const float* __restrict__ eps, int l, float* __restrict__ out, int N)
{
    __shared__ float W1s[D * D], W2s[D * D], b1s[D], b2s[D];
    int t = threadIdx.x;
    for (int i = t; i < D * D; i += 256) { W1s[i] = W1[i]; W2s[i] = W2[i]; }
    if (t < D) { b1s[t] = b1[t]; b2s[t] = b2[t]; }
    __syncthreads();

    int g = t >> 5, j = t & 31;
    int node = blockIdx.x * 8 + g;
    if (node >= N) return;
    int start = node ? row[node - 1] : 0;
    int end = row[node];

    float acc = 0.f;
    for (int k = start; k < end; ++k) {
        int s0 = srcperm[k] & SRC_MASK;
        float e0 = ea[(size_t)eperm[k] * D + j];
        acc += relu_f(x[(size_t)s0 * D + j] + e0);
    }
    float h = (1.0f + eps[l]) * x[(size_t)node * D + j] + acc;
    float a1 = b1s[j];
    #pragma unroll
    for (int kk = 0; kk < D; ++kk)
        a1 = fmaf(__shfl(h, kk, 32), W1s[kk * D + j], a1);
    float y = relu_f(a1);
    float a2 = b2s[j];
    #pragma unroll
    for (int kk = 0; kk < D; ++kk)
        a2 = fmaf(__shfl(y, kk, 32), W2s[kk * D + j], a2);
    out[(size_t)node * D + j] = relu_f(a2);
}

// ===================== atomic fallback path ====================
__global__ void __launch_bounds__(256) gine_scatter_kernel(
    const float* __restrict__ x, const float* __restrict__ ea,
    const int* __restrict__ src, const int* __restrict__ dst,
    float* __restrict__ aggr, int E)
{
    int i = blockIdx.x * blockDim.x + threadIdx.x;
    if (i >= E * 8) return;
    int e = i >> 3, q = i & 7;
    float4 a = reinterpret_cast<const float4*>(ea)[(size_t)e * 8 + q];
    int s = src[e], d = dst[e];
    float4 xv = reinterpret_cast<const float4*>(x)[(size_t)s * 8 + q];
    float* base = aggr + (size_t)d * D + (size_t)q * 4;
    __hip_atomic_fetch_add(base + 0, relu_f(xv.x + a.x), __ATOMIC_RELAXED, __HIP_MEMORY_SCOPE_AGENT);
    __hip_atomic_fetch_add(base + 1, relu_f(xv.y + a.y), __ATOMIC_RELAXED, __HIP_MEMORY_SCOPE_AGENT);
    __hip_atomic_fetch_add(base + 2, relu_f(xv.z + a.z), __ATOMIC_RELAXED, __HIP_MEMORY_SCOPE_AGENT);
    __hip_atomic_fetch_add(base + 3, relu_f(xv.w + a.w), __ATOMIC_RELAXED, __HIP_MEMORY_SCOPE_AGENT);
}

__global__ void __launch_bounds__(256) gine_node_kernel(
    const float* __restrict__ x, const float* __restrict__ aggr,
    const float* __restrict__ W1, const float* __restrict__ b1,
    const float* __restrict__ W2, const float* __restrict__ b2,
    const float* __restrict__ eps, int l, float* __restrict__ out, int N)
{
    __shared__ float W1s[D * D], W2s[D * D], b1s[D], b2s[D];
    __shared__ float hs[8][D], y1s[8][D];
    int t = threadIdx.x;
    for (int i = t; i < D * D; i += 256) { W1s[i] = W1[i]; W2s[i] = W2[i]; }
    if (t < D) { b1s[t] = b1[t]; b2s[t] = b2[t]; }
    float ep1 = 1.0f + eps[l];
    int local = t >> 5, j = t & 31;
    int node = blockIdx.x * 8 + local;
    __syncthreads();
    if (node < N)
        hs[local][j] = ep1 * x[(size_t)node * D + j] + aggr[(size_t)node * D + j];
    __syncthreads();
    if (node < N) {
        float acc = b1s[j];
        #pragma unroll
        for (int k = 0; k < D; ++k) acc = fmaf(hs[local][k], W1s[k * D + j], acc);
        y1s[local][j] = relu_f(acc);
    }
    __syncthreads();
    if (node < N) {
        float acc = b2s[j];
        #pragma unroll
        for (int k = 0; k < D; ++k) acc = fmaf(y1s[local][k], W2s[k * D + j], acc);
        out[(size_t)node * D + j] = relu_f(acc);
    }
}

// ============================== launcher ===============================
extern "C" void kernel_launch(void* const* d_in, const int* in_sizes, int n_in,
                              void* d_out, int out_size, void* d_ws, size_t ws_size,
                              hipStream_t stream) {
    const float* x_in = (const float*)d_in[0];
    const float* ea   = (const float*)d_in[1];
    const int*   ei   = (const int*)d_in[2];
    const float* W1   = (const float*)d_in[3];
    const float* b1   = (const float*)d_in[4];
    const float* W2   = (const float*)d_in[5];
    const float* b2   = (const float*)d_in[6];
    const float* eps  = (const float*)d_in[7];

    int N = in_sizes[0] / D;
    int E = in_sizes[1] / D;
    int L = in_sizes[3] / (D * D);

    const int* src = ei;       // edge_index[0] = message source j
    const int* dst = ei + E;   // edge_index[1] = message target i

    float* out = (float*)d_out;
    char*  ws  = (char*)d_ws;

    size_t off = 0;
    auto take = [&](size_t bytes) -> size_t {
        size_t p = off; off = (off + bytes + 255) & ~(size_t)255; return p;
    };
    size_t o_bufA    = take((size_t)N * D * sizeof(float));
    size_t o_row     = take((size_t)(N + 8) * sizeof(int));
    size_t o_part    = take(1024 * sizeof(int));
    size_t o_srcpk   = take((size_t)E * sizeof(int));
    size_t o_eperm   = take((size_t)E * sizeof(int));
    size_t need_csr  = off;
    size_t o_eah     = take((size_t)E * D * sizeof(unsigned short));
    size_t need_full = off;

    float* bufA  = (float*)(ws + o_bufA);
    int*   row   = (int*)(ws + o_row);
    int*   part  = (int*)(ws + o_part);
    int*   srcpk = (int*)(ws + o_srcpk);
    int*   eperm = (int*)(ws + o_eperm);

    int path = (ws_size >= need_full) ? 2 : (ws_size >= need_csr ? 1 : 0);

    if (path == 0) {
        float* aggr = bufA + (size_t)N * D;   // legacy path (needs 2*N*D)
        const float* cur = x_in;
        for (int l = 0; l < L; ++l) {
            float* nxt = (((L - 1 - l) & 1) == 0) ? out : bufA;
            hipMemsetAsync(aggr, 0, (size_t)N * D * sizeof(float), stream);
            gine_scatter_kernel<<<(E * 8 + 255) / 256, 256, 0, stream>>>(cur, ea, src, dst, aggr, E);
            gine_node_kernel<<<(N + 7) / 8, 256, 0, stream>>>(
                cur, aggr, W1 + (size_t)l * D * D, b1 + (size_t)l * D,
                W2 + (size_t)l * D * D, b2 + (size_t)l * D, eps, l, nxt, N);
            cur = nxt;
        }
        return;
    }

    unsigned* eah = (unsigned*)(ws + o_eah);

    // ---- preprocessing (once per call) ----
    int nb = (N + SCAN_CHUNK - 1) / SCAN_CHUNK;
    hipMemsetAsync(row, 0, (size_t)N * sizeof(int), stream);
    hist_kernel<<<(E + 255) / 256, 256, 0, stream>>>(dst, row, E);
    scan_partial_kernel<<<nb, 256, 0, stream>>>(row, part, N);
    scan_part_exclusive_kernel<<<1, 64, 0, stream>>>(part, nb);
    scan_final_kernel<<<nb, 256, 0, stream>>>(row, part, N);
    place_idx_kernel<<<(E + 255) / 256, 256, 0, stream>>>(
        src, dst, row, srcpk, eperm, E);
    // row[n] is now the inclusive prefix (end offset of node n)
    if (path == 2) {
        gather_convert_kernel<<<(E * 8 + 255) / 256, 256, 0, stream>>>(
            ea, eperm, eah, E);
    }

    const float* cur = x_in;
    for (int l = 0; l < L; ++l) {
        float* nxt = (((L - 1 - l) & 1) == 0) ? out : bufA;
        if (path == 2) {
            gine_fused4_kernel<<<(N + NPB - 1) / NPB, 256, 0, stream>>>(
                cur, eah, srcpk, row,
                W1 + (size_t)l * D * D, b1 + (size_t)l * D,
                W2 + (size_t)l * D * D, b2 + (size_t)l * D, eps, l, nxt, N);
        } else {
            gine_fused_kernel<<<(N + 7) / 8, 256, 0, stream>>>(
                cur, ea, srcpk, eperm, row,
                W1 + (size_t)l * D * D, b1 + (size_t)l * D,
                W2 + (size_t)l * D * D, b2 + (size_t)l * D, eps, l, nxt, N);
        }
        cur = nxt;
    }
}